// Round 7
// baseline (1347.558 us; speedup 1.0000x reference)
//
#include <hip/hip_runtime.h>
#include <stdint.h>

#define B_ 64
#define S_ 512
#define I_ 512
#define H_ 1024
#define O_ 512
#define HB (B_ * H_)     // 65536 elements per hs slot
#define SENT 0x7F80u     // bf16 +inf: tanh output can never equal this

typedef __attribute__((ext_vector_type(8))) short bf16x8;   // 8 bf16 in 4 VGPRs
typedef __attribute__((ext_vector_type(4))) float f32x4;
typedef __attribute__((ext_vector_type(2))) unsigned uint32x2;

__device__ inline unsigned short f2bf(float f) {
    union { float f; unsigned u; } v; v.f = f;
    unsigned r = v.u + 0x7fffu + ((v.u >> 16) & 1u);   // RNE
    return (unsigned short)(r >> 16);
}
__device__ inline float bf2f(unsigned short h) {
    union { unsigned u; float f; } v; v.u = ((unsigned)h) << 16; return v.f;
}

// ---------------------------------------------------------------------------
// Tiled hs layout (bf16, S+1 slots). Element h_t[b][kk]  (b=16g+rr, rr<16):
//   slot t, element offset within slot:
//     g*16384 + (kk>>8)*4096 + ((kk>>5)&7)*512 + (((kk>>3)&3)*16 + rr)*8 + (kk&7)
// Consumer wave w of block (g,*) polls the contiguous 8 KB at [g*16384+w*4096];
// load k's uint4 at unit (k*64+lane) IS the MFMA A-fragment of K-chunk k.
// Producer block (g,j)'s whole 16x64 output tile is the CONTIGUOUS 2 KB at
// [g*16384 + (j>>2)*4096 + (j&3)*1024] -> published as 256 coalesced 8 B stores.
//
// Scope protocol (deadlock-free by construction):
//   - h STORES are always sc0 sc1 (write-through to MALL) -> every value is
//     eventually visible to a system-scope read, unconditionally.
//   - h POLL LOADS start sc0-only (L1 bypass, local-XCD L2 visible). Grid=128
//     with g=bid&7 (g>=4 exits) co-locates each group on one XCD under the
//     empirical bid%8 round-robin; if so, polls are ~300cy L2 RTs not ~1000cy
//     MALL RTs. A wave that fails 64 fast tries escalates to sc0 sc1 for the
//     rest of the step AND permanently (sticky): wrong mapping or unexpected
//     cache semantics degrade to round-5 behavior, never to a hang.
//
// Sentinel detection shortcut: hs only ever holds 0.0, tanh outputs (|v|<=1 ->
// bf16 bit14 clear) or the sentinel 0x7F80 (bit14 SET). "any sentinel" ==
// OR of all dwords has bit 0x4000 in either half. 1 VALU op/dword.
// ---------------------------------------------------------------------------

// ---------------- fp32 -> bf16 convert (x4 vectorized) ----------------
__global__ void k_f2bf4(const float4* __restrict__ src, ushort4* __restrict__ dst, int n4) {
    int i = blockIdx.x * blockDim.x + threadIdx.x;
    if (i < n4) {
        float4 v = src[i];
        ushort4 o;
        o.x = f2bf(v.x); o.y = f2bf(v.y); o.z = f2bf(v.z); o.w = f2bf(v.w);
        dst[i] = o;
    }
}

// ---------------- init: hs slot 0 = 0 (h0), slots 1..S = sentinel ----------------
__global__ void k_init(uint4* __restrict__ hs) {
    size_t i = (size_t)blockIdx.x * blockDim.x + threadIdx.x;   // one uint4 = 8 bf16
    size_t n = (size_t)(S_ + 1) * HB / 8;
    if (i >= n) return;
    unsigned v = (i < HB / 8) ? 0u : (SENT | (SENT << 16));
    hs[i] = (uint4){v, v, v, v};
}

// ---------------- generic 128x128 bf16 MFMA GEMM: C = A(MxK) * B(NxK)^T ----------------
// MODE 0: A plain row-major; C -> xi (S,B,H) bf16 with +bias1+bias2.
// MODE 1: A = tiled hs (slots 1..S decoded per the layout above); C -> out fp32 +bias1.
template <int MODE>
__global__ __launch_bounds__(256) void k_gemm(
    const unsigned short* __restrict__ A, const unsigned short* __restrict__ Bm,
    const float* __restrict__ bias1, const float* __restrict__ bias2,
    void* __restrict__ Cout, int M, int N, int K)
{
    __shared__ unsigned short As[128][40];
    __shared__ unsigned short Bs[128][40];

    const int tid  = threadIdx.x;
    const int m0   = blockIdx.x * 128;
    const int n0   = blockIdx.y * 128;
    const int wave = tid >> 6, lane = tid & 63;
    const int wm   = (wave >> 1) * 64, wn = (wave & 1) * 64;
    const int l16  = lane & 15, q = lane >> 4;

    f32x4 acc[4][4];
#pragma unroll
    for (int a = 0; a < 4; ++a)
#pragma unroll
        for (int b = 0; b < 4; ++b)
            acc[a][b] = (f32x4){0.f, 0.f, 0.f, 0.f};

    for (int k0 = 0; k0 < K; k0 += 32) {
#pragma unroll
        for (int c = 0; c < 2; ++c) {
            int idx = tid + c * 256;
            int row = idx >> 2, col = (idx & 3) * 8;
            if (MODE == 0) {
                *(bf16x8*)&As[row][col] = *(const bf16x8*)&A[(size_t)(m0 + row) * K + k0 + col];
            } else {
                int m = m0 + row, kk = k0 + col;
                int t = m >> 6, b = m & 63;
                size_t E = (size_t)(t + 1) * 65536 + (size_t)(b >> 4) * 16384
                         + (size_t)(kk >> 8) * 4096 + (size_t)((kk >> 5) & 7) * 512
                         + (size_t)((((kk >> 3) & 3) * 16 + (b & 15)) * 8);
                *(bf16x8*)&As[row][col] = *(const bf16x8*)&A[E];
            }
            *(bf16x8*)&Bs[row][col] = *(const bf16x8*)&Bm[(size_t)(n0 + row) * K + k0 + col];
        }
        __syncthreads();

        bf16x8 af[4], bfr[4];
#pragma unroll
        for (int mt = 0; mt < 4; ++mt) af[mt]  = *(const bf16x8*)&As[wm + mt * 16 + l16][q * 8];
#pragma unroll
        for (int nt = 0; nt < 4; ++nt) bfr[nt] = *(const bf16x8*)&Bs[wn + nt * 16 + l16][q * 8];
#pragma unroll
        for (int mt = 0; mt < 4; ++mt)
#pragma unroll
            for (int nt = 0; nt < 4; ++nt)
                acc[mt][nt] = __builtin_amdgcn_mfma_f32_16x16x32_bf16(af[mt], bfr[nt], acc[mt][nt], 0, 0, 0);
        __syncthreads();
    }

    // epilogue; C/D layout: col = lane&15, row = (lane>>4)*4 + reg
#pragma unroll
    for (int mt = 0; mt < 4; ++mt) {
#pragma unroll
        for (int nt = 0; nt < 4; ++nt) {
            int gn = n0 + wn + nt * 16 + l16;
#pragma unroll
            for (int i = 0; i < 4; ++i) {
                int gm = m0 + wm + mt * 16 + q * 4 + i;
                float v = acc[mt][nt][i];
                if (MODE == 0) {
                    v += bias1[gn] + bias2[gn];
                    int bb = gm >> 9, s = gm & (S_ - 1);       // gm = b*S+s
                    ((unsigned short*)Cout)[(s * B_ + bb) * H_ + gn] = f2bf(v);
                } else {
                    v += bias1[gn];
                    int t = gm >> 6, bb = gm & (B_ - 1);        // gm = t*B+b
                    ((float*)Cout)[((bb << 9) + t) * O_ + gn] = v;
                }
            }
        }
    }
}

// ---------------- sequential scan: h_{t+1} = tanh(xi_t + h_t * Wh^T) ----------------
// grid 128: g = bid&7 (>=4 exits -> XCD co-location spacers), j = bid>>3.
// 4 waves/block splitting K 4-ways; round-5 structure; adaptive-scope poll.
__global__ __launch_bounds__(256, 1) void k_scan(
    const unsigned short* __restrict__ xi,   // (S,B,H) bf16
    const unsigned short* __restrict__ Wh,   // (H,H) bf16
    unsigned short* __restrict__ hs)         // (S+1) tiled slots, 1..S = sentinel
{
    __shared__ f32x4 part[2][4][4][64];      // [buf][producer wave][tile n][lane] = 32 KiB

    const int bid = blockIdx.x;
    const int g   = bid & 7;                 // batch group: rows 16g..16g+15
    if (g >= 4) return;                      // spacer blocks (XCD co-location)
    const int j   = bid >> 3;                // col block:   cols 64j..64j+63
    const int n0  = j * 64;
    const int r0  = g * 16;
    const int tid = threadIdx.x;
    const int wave = tid >> 6, lane = tid & 63;
    const int l16 = lane & 15, q = lane >> 4;
    const int kbase = wave * 256;            // this wave's K-quarter

    // ---- preload Wh B-fragments (loop-invariant):
    // lane (l16,q) holds Wh[n0+n*16+l16][kbase + ks*32 + q*8 .. +8]
    bf16x8 wreg[4][8];
#pragma unroll
    for (int n = 0; n < 4; ++n)
#pragma unroll
        for (int ks = 0; ks < 8; ++ks)
            wreg[n][ks] = *(const bf16x8*)&Wh[(size_t)(n0 + n * 16 + l16) * H_ + kbase + ks * 32 + q * 8];

    // poll region for this wave: contiguous 8 KB at slot*65536 + g*16384 + wave*4096
    const size_t wavebase = (size_t)g * 16384 + (size_t)wave * 4096;

    // ---- output-finalize constants: thread T owns elements [4T..4T+4) of the
    // block's contiguous 1024-element region (verified bijection, round 4).
    const int c_rel = tid >> 7;
    const int u  = (tid >> 1) & 63;
    const int qo = u >> 4, qq = (u >> 2) & 3, ii = u & 3;
    const int nn = (c_rel << 1) | (qo >> 1);
    const int lb = (qq << 4) | ((qo & 1) << 3) | ((tid & 1) << 2);   // lane of c=0
    const int row  = qq * 4 + ii;                                     // row in group
    const int colb = n0 + nn * 16 + ((qo & 1) << 3) + ((tid & 1) << 2); // col of c=0
    const size_t regbase = (size_t)g * 16384 + (size_t)(j >> 2) * 4096
                         + (size_t)(j & 3) * 1024;                    // block's 2KB region

    int fastBudget = 64;                     // sticky: 0 once a slow completion seen

    for (int t = 0; t < S_; ++t) {
        // xi prefetch: ONE 8 B load per thread (4 consecutive bf16 of one row)
        uint32x2 xv = *(const uint32x2*)&xi[(size_t)t * HB + (size_t)(r0 + row) * H_ + colb];

        // poll-load this wave's A-fragments: 8 contiguous lane-consecutive 1 KB loads.
        // hv[k] IS the A-fragment for K-chunk k. Fast tries = sc0 (local-L2 scope);
        // after fastBudget failures, escalate to sc0 sc1 (MALL scope, always sees
        // the write-through stores). Escalation is sticky across steps.
        const char* hb = (const char*)hs + 2 * ((size_t)t * 65536 + wavebase);
        uint4 hv[8];
        int tries = fastBudget;
        for (;;) {
            if (tries > 0) {
#pragma unroll
                for (int k = 0; k < 8; ++k) {
                    const char* a = hb + (size_t)(k * 64 + lane) * 16;
                    asm volatile("global_load_dwordx4 %0, %1, off sc0"
                                 : "=v"(hv[k]) : "v"(a));
                }
            } else {
#pragma unroll
                for (int k = 0; k < 8; ++k) {
                    const char* a = hb + (size_t)(k * 64 + lane) * 16;
                    asm volatile("global_load_dwordx4 %0, %1, off sc0 sc1"
                                 : "=v"(hv[k]) : "v"(a));
                }
            }
            asm volatile("s_waitcnt vmcnt(0)" ::: "memory");
            __builtin_amdgcn_sched_barrier(0);
            // bit14-OR sentinel test: reals (tanh, 0.0) never set 0x4000 in a
            // bf16 half; sentinel 0x7F80 does.
            unsigned acc_or = 0;
#pragma unroll
            for (int k = 0; k < 8; ++k)
                acc_or |= (hv[k].x | hv[k].y) | (hv[k].z | hv[k].w);
            if (__ballot((acc_or & 0x40004000u) != 0u) == 0ull) break;
            --tries;
        }
        if (tries <= 0) fastBudget = 0;      // completed at MALL scope -> stay slow

        // 32 MFMAs: full 16x64 output tile over this wave's K-quarter
        f32x4 acc[4];
#pragma unroll
        for (int n = 0; n < 4; ++n) acc[n] = (f32x4){0.f, 0.f, 0.f, 0.f};
#pragma unroll
        for (int ks = 0; ks < 8; ++ks) {
            bf16x8 av = __builtin_bit_cast(bf16x8, hv[ks]);
#pragma unroll
            for (int n = 0; n < 4; ++n)
                acc[n] = __builtin_amdgcn_mfma_f32_16x16x32_bf16(av, wreg[n][ks], acc[n], 0, 0, 0);
        }

        // cross-wave K-reduction exchange (lane-consecutive b128, conflict-free),
        // double-buffered on t&1 -> single barrier per step.
        const int p = t & 1;
#pragma unroll
        for (int n = 0; n < 4; ++n)
            part[p][wave][n][lane] = acc[n];
        __syncthreads();

        // gather-finalize, bank-conflict-free: instruction slot c reads element
        // (c^qq) -> banks (tid&1)*16 + (c^qq)*4 + ii cover all 32, 2-way max.
        float s2[4] = {0.f, 0.f, 0.f, 0.f};
#pragma unroll
        for (int ws = 0; ws < 4; ++ws) {
            const float* pp = (const float*)&part[p][ws][nn][lb];
#pragma unroll
            for (int c = 0; c < 4; ++c)
                s2[c] += pp[((c ^ qq) << 2) + ii];
        }
        // un-butterfly: element e = s2[e ^ qq]  (static cndmask network)
        const bool b0 = (qq & 1) != 0, b1 = (qq & 2) != 0;
        float t0 = b0 ? s2[1] : s2[0], t1 = b0 ? s2[0] : s2[1];
        float t2 = b0 ? s2[3] : s2[2], t3 = b0 ? s2[2] : s2[3];
        float e0 = b1 ? t2 : t0, e1 = b1 ? t3 : t1;
        float e2 = b1 ? t0 : t2, e3 = b1 ? t1 : t3;
        float s[4] = { e0, e1, e2, e3 };

        // +xi, tanh (branch-free), pack 4 bf16 -> one coalesced 8 B store
        float xf[4] = { bf2f((unsigned short)(xv[0] & 0xffffu)),
                        bf2f((unsigned short)(xv[0] >> 16)),
                        bf2f((unsigned short)(xv[1] & 0xffffu)),
                        bf2f((unsigned short)(xv[1] >> 16)) };
        unsigned short h16[4];
#pragma unroll
        for (int c = 0; c < 4; ++c) {
            float x = s[c] + xf[c];
            float e = __expf(2.f * x);
            h16[c] = f2bf(1.f - 2.f / (e + 1.f));
        }
        uint32x2 val;
        val[0] = (unsigned)h16[0] | ((unsigned)h16[1] << 16);
        val[1] = (unsigned)h16[2] | ((unsigned)h16[3] << 16);
        const unsigned short* ap = hs + (size_t)(t + 1) * 65536 + regbase + (size_t)tid * 4;
        asm volatile("global_store_dwordx2 %0, %1, off sc0 sc1"
                     :: "v"(ap), "v"(val) : "memory");
        // no drain: next poll's vmcnt(0) covers it; visibility is eventual
    }
}

// ---------------- h_last: tiled hs slot S -> fp32 (B,H) ----------------
__global__ void k_hlast(const unsigned short* __restrict__ hsT, float* __restrict__ out) {
    int i = blockIdx.x * blockDim.x + threadIdx.x;   // i = b*1024 + kk
    if (i >= HB) return;
    int b = i >> 10, kk = i & 1023;
    size_t E = (size_t)S_ * 65536 + (size_t)(b >> 4) * 16384
             + (size_t)(kk >> 8) * 4096 + (size_t)((kk >> 5) & 7) * 512
             + (size_t)((((kk >> 3) & 3) * 16 + (b & 15)) * 8) + (kk & 7);
    out[i] = bf2f(hsT[E]);
}

extern "C" void kernel_launch(void* const* d_in, const int* in_sizes, int n_in,
                              void* d_out, int out_size, void* d_ws, size_t ws_size,
                              hipStream_t stream) {
    const float* x  = (const float*)d_in[0];
    const float* Wi = (const float*)d_in[1];
    const float* bi = (const float*)d_in[2];
    const float* Wh = (const float*)d_in[3];
    const float* bh = (const float*)d_in[4];
    const float* Wo = (const float*)d_in[5];
    const float* bo = (const float*)d_in[6];
    float* out = (float*)d_out;

    char* p = (char*)d_ws;
    unsigned short* x_bf  = (unsigned short*)p; p += (size_t)B_ * S_ * I_ * 2;
    unsigned short* Wi_bf = (unsigned short*)p; p += (size_t)H_ * I_ * 2;
    unsigned short* Wh_bf = (unsigned short*)p; p += (size_t)H_ * H_ * 2;
    unsigned short* Wo_bf = (unsigned short*)p; p += (size_t)O_ * H_ * 2;
    unsigned short* xi    = (unsigned short*)p; p += (size_t)S_ * B_ * H_ * 2;
    unsigned short* hs    = (unsigned short*)p; p += (size_t)(S_ + 1) * HB * 2;

    int n4;
    n4 = B_ * S_ * I_ / 4;
    k_f2bf4<<<(n4 + 255) / 256, 256, 0, stream>>>((const float4*)x,  (ushort4*)x_bf,  n4);
    n4 = H_ * I_ / 4;
    k_f2bf4<<<(n4 + 255) / 256, 256, 0, stream>>>((const float4*)Wi, (ushort4*)Wi_bf, n4);
    n4 = H_ * H_ / 4;
    k_f2bf4<<<(n4 + 255) / 256, 256, 0, stream>>>((const float4*)Wh, (ushort4*)Wh_bf, n4);
    n4 = O_ * H_ / 4;
    k_f2bf4<<<(n4 + 255) / 256, 256, 0, stream>>>((const float4*)Wo, (ushort4*)Wo_bf, n4);

    // hs: slot 0 = zeros, slots 1..S = bf16 +inf sentinel (layout-independent fill)
    {
        size_t n = (size_t)(S_ + 1) * HB / 8;
        k_init<<<(unsigned)((n + 255) / 256), 256, 0, stream>>>((uint4*)hs);
    }

    // xi = x * Wi^T + bi + bh   (M=32768, N=1024, K=512)
    k_gemm<0><<<dim3(B_ * S_ / 128, H_ / 128), 256, 0, stream>>>(
        x_bf, Wi_bf, bi, bh, (void*)xi, B_ * S_, H_, I_);

    // sequential scan: grid 128 (64 worker + 64 spacer blocks for XCD co-location)
    k_scan<<<128, 256, 0, stream>>>(xi, Wh_bf, hs);

    // out = hs(tiled, slots 1..S) * Wo^T + bo   (M=32768, N=512, K=1024)
    k_gemm<1><<<dim3(B_ * S_ / 128, O_ / 128), 256, 0, stream>>>(
        hs, Wo_bf, bo, nullptr, (void*)out, B_ * S_, O_, H_);

    // h_last
    k_hlast<<<(HB + 255) / 256, 256, 0, stream>>>(hs, out + (size_t)B_ * S_ * O_);
}

// Round 8
// 973.972 us; speedup vs baseline: 1.3836x; 1.3836x over previous
//
#include <hip/hip_runtime.h>
#include <stdint.h>

#define B_ 64
#define S_ 512
#define I_ 512
#define H_ 1024
#define O_ 512
#define HB (B_ * H_)     // 65536 elements per hs slot
#define SENT 0x7F80u     // bf16 +inf: tanh output can never equal this

typedef __attribute__((ext_vector_type(8))) short bf16x8;   // 8 bf16 in 4 VGPRs
typedef __attribute__((ext_vector_type(4))) float f32x4;
typedef __attribute__((ext_vector_type(2))) unsigned uint32x2;

__device__ inline unsigned short f2bf(float f) {
    union { float f; unsigned u; } v; v.f = f;
    unsigned r = v.u + 0x7fffu + ((v.u >> 16) & 1u);   // RNE
    return (unsigned short)(r >> 16);
}
__device__ inline float bf2f(unsigned short h) {
    union { unsigned u; float f; } v; v.u = ((unsigned)h) << 16; return v.f;
}

// ---------------------------------------------------------------------------
// Tiled hs layout (bf16, S+1 slots). Element h_t[b][kk]  (b=16g+rr, rr<16):
//   slot t, element offset within slot:
//     g*16384 + (kk>>8)*4096 + ((kk>>5)&7)*512 + (((kk>>3)&3)*16 + rr)*8 + (kk&7)
// Consumer wave w of block (g,*) polls the contiguous 8 KB at [g*16384+w*4096];
// load k's uint4 at unit (k*64+lane) IS the MFMA A-fragment of K-chunk k.
// Producer block (g,j)'s whole 16x64 output tile is the CONTIGUOUS 2 KB at
// [g*16384 + (j>>2)*4096 + (j&3)*1024] -> published as 256 coalesced 8 B stores.
//
// Round-7 lesson: XCD-co-located sc0 polling saturates the local L2 (FETCH
// dropped 140->99 MB but time rose) — poll-storm traffic, not poll latency,
// is the constraint. Reverted to round-5 MALL protocol (sc0 sc1 both sides,
// workers spread over all 8 XCDs).
//
// NEW (round 8): xi is software-pipelined one step ahead. Previously the xi
// load was issued at the top of the step and the poll's vmcnt(0) waited for
// its ~900cy HBM miss EVERY step. Now the t+1 load issues right after the
// poll breaks and hides under MFMA+reduce+publish+next-poll.
//
// Sentinel detection shortcut: hs only ever holds 0.0, tanh outputs (|v|<=1 ->
// bf16 bit14 clear) or the sentinel 0x7F80 (bit14 SET). "any sentinel" ==
// OR of all dwords has bit 0x4000 in either half. 1 VALU op/dword.
// ---------------------------------------------------------------------------

// ---------------- fp32 -> bf16 convert (x4 vectorized) ----------------
__global__ void k_f2bf4(const float4* __restrict__ src, ushort4* __restrict__ dst, int n4) {
    int i = blockIdx.x * blockDim.x + threadIdx.x;
    if (i < n4) {
        float4 v = src[i];
        ushort4 o;
        o.x = f2bf(v.x); o.y = f2bf(v.y); o.z = f2bf(v.z); o.w = f2bf(v.w);
        dst[i] = o;
    }
}

// ---------------- init: hs slot 0 = 0 (h0), slots 1..S = sentinel ----------------
__global__ void k_init(uint4* __restrict__ hs) {
    size_t i = (size_t)blockIdx.x * blockDim.x + threadIdx.x;   // one uint4 = 8 bf16
    size_t n = (size_t)(S_ + 1) * HB / 8;
    if (i >= n) return;
    unsigned v = (i < HB / 8) ? 0u : (SENT | (SENT << 16));
    hs[i] = (uint4){v, v, v, v};
}

// ---------------- generic 128x128 bf16 MFMA GEMM: C = A(MxK) * B(NxK)^T ----------------
// MODE 0: A plain row-major; C -> xi (S,B,H) bf16 with +bias1+bias2.
// MODE 1: A = tiled hs (slots 1..S decoded per the layout above); C -> out fp32 +bias1.
template <int MODE>
__global__ __launch_bounds__(256) void k_gemm(
    const unsigned short* __restrict__ A, const unsigned short* __restrict__ Bm,
    const float* __restrict__ bias1, const float* __restrict__ bias2,
    void* __restrict__ Cout, int M, int N, int K)
{
    __shared__ unsigned short As[128][40];
    __shared__ unsigned short Bs[128][40];

    const int tid  = threadIdx.x;
    const int m0   = blockIdx.x * 128;
    const int n0   = blockIdx.y * 128;
    const int wave = tid >> 6, lane = tid & 63;
    const int wm   = (wave >> 1) * 64, wn = (wave & 1) * 64;
    const int l16  = lane & 15, q = lane >> 4;

    f32x4 acc[4][4];
#pragma unroll
    for (int a = 0; a < 4; ++a)
#pragma unroll
        for (int b = 0; b < 4; ++b)
            acc[a][b] = (f32x4){0.f, 0.f, 0.f, 0.f};

    for (int k0 = 0; k0 < K; k0 += 32) {
#pragma unroll
        for (int c = 0; c < 2; ++c) {
            int idx = tid + c * 256;
            int row = idx >> 2, col = (idx & 3) * 8;
            if (MODE == 0) {
                *(bf16x8*)&As[row][col] = *(const bf16x8*)&A[(size_t)(m0 + row) * K + k0 + col];
            } else {
                int m = m0 + row, kk = k0 + col;
                int t = m >> 6, b = m & 63;
                size_t E = (size_t)(t + 1) * 65536 + (size_t)(b >> 4) * 16384
                         + (size_t)(kk >> 8) * 4096 + (size_t)((kk >> 5) & 7) * 512
                         + (size_t)((((kk >> 3) & 3) * 16 + (b & 15)) * 8);
                *(bf16x8*)&As[row][col] = *(const bf16x8*)&A[E];
            }
            *(bf16x8*)&Bs[row][col] = *(const bf16x8*)&Bm[(size_t)(n0 + row) * K + k0 + col];
        }
        __syncthreads();

        bf16x8 af[4], bfr[4];
#pragma unroll
        for (int mt = 0; mt < 4; ++mt) af[mt]  = *(const bf16x8*)&As[wm + mt * 16 + l16][q * 8];
#pragma unroll
        for (int nt = 0; nt < 4; ++nt) bfr[nt] = *(const bf16x8*)&Bs[wn + nt * 16 + l16][q * 8];
#pragma unroll
        for (int mt = 0; mt < 4; ++mt)
#pragma unroll
            for (int nt = 0; nt < 4; ++nt)
                acc[mt][nt] = __builtin_amdgcn_mfma_f32_16x16x32_bf16(af[mt], bfr[nt], acc[mt][nt], 0, 0, 0);
        __syncthreads();
    }

    // epilogue; C/D layout: col = lane&15, row = (lane>>4)*4 + reg
#pragma unroll
    for (int mt = 0; mt < 4; ++mt) {
#pragma unroll
        for (int nt = 0; nt < 4; ++nt) {
            int gn = n0 + wn + nt * 16 + l16;
#pragma unroll
            for (int i = 0; i < 4; ++i) {
                int gm = m0 + wm + mt * 16 + q * 4 + i;
                float v = acc[mt][nt][i];
                if (MODE == 0) {
                    v += bias1[gn] + bias2[gn];
                    int bb = gm >> 9, s = gm & (S_ - 1);       // gm = b*S+s
                    ((unsigned short*)Cout)[(s * B_ + bb) * H_ + gn] = f2bf(v);
                } else {
                    v += bias1[gn];
                    int t = gm >> 6, bb = gm & (B_ - 1);        // gm = t*B+b
                    ((float*)Cout)[((bb << 9) + t) * O_ + gn] = v;
                }
            }
        }
    }
}

// ---------------- sequential scan: h_{t+1} = tanh(xi_t + h_t * Wh^T) ----------------
// 4 batch-groups x 16 col-blocks (grid 64, round-5 spread), 4 waves/block
// splitting K 4-ways; MALL-scope protocol; xi pipelined one step ahead.
__global__ __launch_bounds__(256, 1) void k_scan(
    const unsigned short* __restrict__ xi,   // (S,B,H) bf16
    const unsigned short* __restrict__ Wh,   // (H,H) bf16
    unsigned short* __restrict__ hs)         // (S+1) tiled slots, 1..S = sentinel
{
    __shared__ f32x4 part[2][4][4][64];      // [buf][producer wave][tile n][lane] = 32 KiB

    const int bid = blockIdx.x;
    const int g   = bid & 3;                 // batch group: rows 16g..16g+15
    const int j   = bid >> 2;                // col block:   cols 64j..64j+63
    const int n0  = j * 64;
    const int r0  = g * 16;
    const int tid = threadIdx.x;
    const int wave = tid >> 6, lane = tid & 63;
    const int l16 = lane & 15, q = lane >> 4;
    const int kbase = wave * 256;            // this wave's K-quarter

    // ---- preload Wh B-fragments (loop-invariant):
    // lane (l16,q) holds Wh[n0+n*16+l16][kbase + ks*32 + q*8 .. +8]
    bf16x8 wreg[4][8];
#pragma unroll
    for (int n = 0; n < 4; ++n)
#pragma unroll
        for (int ks = 0; ks < 8; ++ks)
            wreg[n][ks] = *(const bf16x8*)&Wh[(size_t)(n0 + n * 16 + l16) * H_ + kbase + ks * 32 + q * 8];

    // poll region for this wave: contiguous 8 KB at slot*65536 + g*16384 + wave*4096
    const size_t wavebase = (size_t)g * 16384 + (size_t)wave * 4096;

    // ---- output-finalize constants: thread T owns elements [4T..4T+4) of the
    // block's contiguous 1024-element region (verified bijection, round 4).
    const int c_rel = tid >> 7;
    const int u  = (tid >> 1) & 63;
    const int qo = u >> 4, qq = (u >> 2) & 3, ii = u & 3;
    const int nn = (c_rel << 1) | (qo >> 1);
    const int lb = (qq << 4) | ((qo & 1) << 3) | ((tid & 1) << 2);   // lane of c=0
    const int row  = qq * 4 + ii;                                     // row in group
    const int colb = n0 + nn * 16 + ((qo & 1) << 3) + ((tid & 1) << 2); // col of c=0
    const size_t regbase = (size_t)g * 16384 + (size_t)(j >> 2) * 4096
                         + (size_t)(j & 3) * 1024;                    // block's 2KB region

    // xi pipeline: this thread's 8 B slice, advancing HB elements per step.
    // Prologue load for t=0; inside the loop we load t+1 right after the poll
    // breaks so the ~900cy HBM miss hides under compute+publish+next-poll.
    // (At t=S_-1 the prefetch reads the start of hs — mapped, value unused.)
    const unsigned short* xip = xi + (size_t)(r0 + row) * H_ + colb;
    uint32x2 xv = *(const uint32x2*)xip;

    for (int t = 0; t < S_; ++t) {
        // poll-load this wave's A-fragments: 8 contiguous lane-consecutive 1 KB loads.
        // hv[k] IS the A-fragment for K-chunk k: lane(l16,q) = h[r0+l16][kbase+k*32+q*8..+8]
        const char* hb = (const char*)hs + 2 * ((size_t)t * 65536 + wavebase);
        uint4 hv[8];
        for (;;) {
#pragma unroll
            for (int k = 0; k < 8; ++k) {
                const char* a = hb + (size_t)(k * 64 + lane) * 16;
                asm volatile("global_load_dwordx4 %0, %1, off sc0 sc1"
                             : "=v"(hv[k]) : "v"(a));
            }
            asm volatile("s_waitcnt vmcnt(0)" ::: "memory");
            __builtin_amdgcn_sched_barrier(0);
            // bit14-OR sentinel test: reals (tanh, 0.0) never set 0x4000 in a
            // bf16 half; sentinel 0x7F80 does.
            unsigned acc_or = 0;
#pragma unroll
            for (int k = 0; k < 8; ++k)
                acc_or |= (hv[k].x | hv[k].y) | (hv[k].z | hv[k].w);
            if (__ballot((acc_or & 0x40004000u) != 0u) == 0ull) break;
        }

        // issue next step's xi load NOW (hides under MFMA+reduce+publish+poll)
        uint32x2 xv_next = *(const uint32x2*)(xip + (size_t)(t + 1) * HB);

        // 32 MFMAs: full 16x64 output tile over this wave's K-quarter
        f32x4 acc[4];
#pragma unroll
        for (int n = 0; n < 4; ++n) acc[n] = (f32x4){0.f, 0.f, 0.f, 0.f};
#pragma unroll
        for (int ks = 0; ks < 8; ++ks) {
            bf16x8 av = __builtin_bit_cast(bf16x8, hv[ks]);
#pragma unroll
            for (int n = 0; n < 4; ++n)
                acc[n] = __builtin_amdgcn_mfma_f32_16x16x32_bf16(av, wreg[n][ks], acc[n], 0, 0, 0);
        }

        // cross-wave K-reduction exchange (lane-consecutive b128, conflict-free),
        // double-buffered on t&1 -> single barrier per step.
        const int p = t & 1;
#pragma unroll
        for (int n = 0; n < 4; ++n)
            part[p][wave][n][lane] = acc[n];
        __syncthreads();

        // gather-finalize, bank-conflict-free: instruction slot c reads element
        // (c^qq) -> banks (tid&1)*16 + (c^qq)*4 + ii cover all 32, 2-way max.
        float s2[4] = {0.f, 0.f, 0.f, 0.f};
#pragma unroll
        for (int ws = 0; ws < 4; ++ws) {
            const float* pp = (const float*)&part[p][ws][nn][lb];
#pragma unroll
            for (int c = 0; c < 4; ++c)
                s2[c] += pp[((c ^ qq) << 2) + ii];
        }
        // un-butterfly: element e = s2[e ^ qq]  (static cndmask network)
        const bool b0 = (qq & 1) != 0, b1 = (qq & 2) != 0;
        float t0 = b0 ? s2[1] : s2[0], t1 = b0 ? s2[0] : s2[1];
        float t2 = b0 ? s2[3] : s2[2], t3 = b0 ? s2[2] : s2[3];
        float e0 = b1 ? t2 : t0, e1 = b1 ? t3 : t1;
        float e2 = b1 ? t0 : t2, e3 = b1 ? t1 : t3;
        float s[4] = { e0, e1, e2, e3 };

        // +xi, tanh (branch-free), pack 4 bf16 -> one coalesced 8 B store
        float xf[4] = { bf2f((unsigned short)(xv[0] & 0xffffu)),
                        bf2f((unsigned short)(xv[0] >> 16)),
                        bf2f((unsigned short)(xv[1] & 0xffffu)),
                        bf2f((unsigned short)(xv[1] >> 16)) };
        unsigned short h16[4];
#pragma unroll
        for (int c = 0; c < 4; ++c) {
            float x = s[c] + xf[c];
            float e = __expf(2.f * x);
            h16[c] = f2bf(1.f - 2.f / (e + 1.f));
        }
        uint32x2 val;
        val[0] = (unsigned)h16[0] | ((unsigned)h16[1] << 16);
        val[1] = (unsigned)h16[2] | ((unsigned)h16[3] << 16);
        const unsigned short* ap = hs + (size_t)(t + 1) * 65536 + regbase + (size_t)tid * 4;
        asm volatile("global_store_dwordx2 %0, %1, off sc0 sc1"
                     :: "v"(ap), "v"(val) : "memory");
        // no drain: next poll's vmcnt(0) covers it; visibility is eventual

        xv = xv_next;
    }
}

// ---------------- h_last: tiled hs slot S -> fp32 (B,H) ----------------
__global__ void k_hlast(const unsigned short* __restrict__ hsT, float* __restrict__ out) {
    int i = blockIdx.x * blockDim.x + threadIdx.x;   // i = b*1024 + kk
    if (i >= HB) return;
    int b = i >> 10, kk = i & 1023;
    size_t E = (size_t)S_ * 65536 + (size_t)(b >> 4) * 16384
             + (size_t)(kk >> 8) * 4096 + (size_t)((kk >> 5) & 7) * 512
             + (size_t)((((kk >> 3) & 3) * 16 + (b & 15)) * 8) + (kk & 7);
    out[i] = bf2f(hsT[E]);
}

extern "C" void kernel_launch(void* const* d_in, const int* in_sizes, int n_in,
                              void* d_out, int out_size, void* d_ws, size_t ws_size,
                              hipStream_t stream) {
    const float* x  = (const float*)d_in[0];
    const float* Wi = (const float*)d_in[1];
    const float* bi = (const float*)d_in[2];
    const float* Wh = (const float*)d_in[3];
    const float* bh = (const float*)d_in[4];
    const float* Wo = (const float*)d_in[5];
    const float* bo = (const float*)d_in[6];
    float* out = (float*)d_out;

    char* p = (char*)d_ws;
    unsigned short* x_bf  = (unsigned short*)p; p += (size_t)B_ * S_ * I_ * 2;
    unsigned short* Wi_bf = (unsigned short*)p; p += (size_t)H_ * I_ * 2;
    unsigned short* Wh_bf = (unsigned short*)p; p += (size_t)H_ * H_ * 2;
    unsigned short* Wo_bf = (unsigned short*)p; p += (size_t)O_ * H_ * 2;
    unsigned short* xi    = (unsigned short*)p; p += (size_t)S_ * B_ * H_ * 2;
    unsigned short* hs    = (unsigned short*)p; p += (size_t)(S_ + 1) * HB * 2;

    int n4;
    n4 = B_ * S_ * I_ / 4;
    k_f2bf4<<<(n4 + 255) / 256, 256, 0, stream>>>((const float4*)x,  (ushort4*)x_bf,  n4);
    n4 = H_ * I_ / 4;
    k_f2bf4<<<(n4 + 255) / 256, 256, 0, stream>>>((const float4*)Wi, (ushort4*)Wi_bf, n4);
    n4 = H_ * H_ / 4;
    k_f2bf4<<<(n4 + 255) / 256, 256, 0, stream>>>((const float4*)Wh, (ushort4*)Wh_bf, n4);
    n4 = O_ * H_ / 4;
    k_f2bf4<<<(n4 + 255) / 256, 256, 0, stream>>>((const float4*)Wo, (ushort4*)Wo_bf, n4);

    // hs: slot 0 = zeros, slots 1..S = bf16 +inf sentinel (layout-independent fill)
    {
        size_t n = (size_t)(S_ + 1) * HB / 8;
        k_init<<<(unsigned)((n + 255) / 256), 256, 0, stream>>>((uint4*)hs);
    }

    // xi = x * Wi^T + bi + bh   (M=32768, N=1024, K=512)
    k_gemm<0><<<dim3(B_ * S_ / 128, H_ / 128), 256, 0, stream>>>(
        x_bf, Wi_bf, bi, bh, (void*)xi, B_ * S_, H_, I_);

    // sequential scan: 64 blocks = 4 batch-groups x 16 col-blocks, static 32 KiB LDS
    k_scan<<<64, 256, 0, stream>>>(xi, Wh_bf, hs);

    // out = hs(tiled, slots 1..S) * Wo^T + bo   (M=32768, N=512, K=1024)
    k_gemm<1><<<dim3(B_ * S_ / 128, O_ / 128), 256, 0, stream>>>(
        hs, Wo_bf, bo, nullptr, (void*)out, B_ * S_, O_, H_);

    // h_last
    k_hlast<<<(HB + 255) / 256, 256, 0, stream>>>(hs, out + (size_t)B_ * S_ * O_);
}